// Round 1
// baseline (481.052 us; speedup 1.0000x reference)
//
#include <hip/hip_runtime.h>

// Fused causal attention block: qkv = x@Wqkv+b; flash-attn(causal); out = attn@Wout+b
// B=2, S=2048, D=2048, H=16, Dh=128. All GEMM/attn compute in bf16 MFMA, fp32 accum.

typedef unsigned short u16;
typedef __attribute__((ext_vector_type(8))) short bf16x8;   // 8 bf16 (4 VGPRs)
typedef __attribute__((ext_vector_type(4))) float f32x4;

#define MFMA(a, b, c) __builtin_amdgcn_mfma_f32_16x16x32_bf16((a), (b), (c), 0, 0, 0)

__device__ __forceinline__ u16 f2bf(float f) {           // RNE fp32->bf16
    unsigned u = __builtin_bit_cast(unsigned, f);
    u += 0x7fffu + ((u >> 16) & 1u);
    return (u16)(u >> 16);
}

__device__ __forceinline__ void gload16(const void* g, void* l) {
    __builtin_amdgcn_global_load_lds(
        (const __attribute__((address_space(1))) void*)g,
        (__attribute__((address_space(3))) void*)l, 16, 0, 0);
}

// ---------------- cast / transpose helpers ----------------

__global__ __launch_bounds__(256) void k_cast(const float* __restrict__ src,
                                              u16* __restrict__ dst, int n4) {
    int i = blockIdx.x * 256 + threadIdx.x;
    if (i >= n4) return;
    float4 a = ((const float4*)src)[i];
    ushort4 r;
    r.x = f2bf(a.x); r.y = f2bf(a.y); r.z = f2bf(a.z); r.w = f2bf(a.w);
    ((ushort4*)dst)[i] = r;
}

// src [rows][cols] fp32 -> dst [cols][rows] bf16
__global__ __launch_bounds__(256) void k_castT(const float* __restrict__ src,
                                               u16* __restrict__ dst, int rows, int cols) {
    __shared__ float t[32][33];
    int c0 = blockIdx.x * 32, r0 = blockIdx.y * 32;
    int tx = threadIdx.x, ty = threadIdx.y;
#pragma unroll
    for (int i = 0; i < 4; ++i)
        t[ty + 8 * i][tx] = src[(size_t)(r0 + ty + 8 * i) * cols + (c0 + tx)];
    __syncthreads();
#pragma unroll
    for (int i = 0; i < 4; ++i)
        dst[(size_t)(c0 + ty + 8 * i) * rows + (r0 + tx)] = f2bf(t[tx][ty + 8 * i]);
}

// v [head][2048][128] bf16 -> vT [head][128][2048] bf16
__global__ __launch_bounds__(256) void k_transv(const u16* __restrict__ v,
                                                u16* __restrict__ vT) {
    __shared__ u16 t[32][33];
    int head = blockIdx.z;
    int s0 = blockIdx.x * 32, d0 = blockIdx.y * 32;
    const u16* vp = v + (size_t)head * 2048 * 128;
    u16* op = vT + (size_t)head * 128 * 2048;
    int tx = threadIdx.x, ty = threadIdx.y;
#pragma unroll
    for (int i = 0; i < 4; ++i)
        t[ty + 8 * i][tx] = vp[(size_t)(s0 + ty + 8 * i) * 128 + d0 + tx];
    __syncthreads();
#pragma unroll
    for (int i = 0; i < 4; ++i)
        op[(size_t)(d0 + ty + 8 * i) * 2048 + (s0 + tx)] = t[tx][ty + 8 * i];
}

// ---------------- GEMM core (m97 structure): C[128x128] tile, BK=32 ----------------
// A [M][K] bf16 row-major; BT [N][K] bf16 row-major (i.e. B transposed).

template <int K>
__device__ __forceinline__ void gemm_core(const u16* __restrict__ A,
                                          const u16* __restrict__ BT,
                                          int m0, int n0,
                                          f32x4 (&acc)[4][4],
                                          u16* As, u16* Bs) {
    const int tid = threadIdx.x, wave = tid >> 6, lane = tid & 63;
    const int wr = (wave >> 1) * 64, wc = (wave & 1) * 64;
    for (int k0 = 0; k0 < K; k0 += 32) {
        __syncthreads();   // previous compute done before LDS overwrite
#pragma unroll
        for (int i = 0; i < 2; ++i) {
            int cb = (i * 4 + wave) * 64;         // wave-uniform chunk base
            int c = cb + lane;
            int row = c >> 2, kk = (c & 3) * 8;   // 4 x 16B chunks per 32-elem row
            gload16(A + (size_t)(m0 + row) * K + k0 + kk, As + cb * 8);
            gload16(BT + (size_t)(n0 + row) * K + k0 + kk, Bs + cb * 8);
        }
        __syncthreads();   // vmcnt(0) drain before reads
        bf16x8 a[4], b[4];
#pragma unroll
        for (int m = 0; m < 4; ++m)
            a[m] = *(const bf16x8*)(As + (wr + m * 16 + (lane & 15)) * 32 + (lane >> 4) * 8);
#pragma unroll
        for (int n = 0; n < 4; ++n)
            b[n] = *(const bf16x8*)(Bs + (wc + n * 16 + (lane & 15)) * 32 + (lane >> 4) * 8);
#pragma unroll
        for (int m = 0; m < 4; ++m)
#pragma unroll
            for (int n = 0; n < 4; ++n)
                acc[m][n] = MFMA(a[m], b[n], acc[m][n]);
    }
}

// GEMM1: qkv = x@Wqkv + bqkv, scattered into q/k/v [B*H][S][Dh] bf16
__global__ __launch_bounds__(256) void k_gemm_qkv(const u16* __restrict__ A,
                                                  const u16* __restrict__ BT,
                                                  const float* __restrict__ bias,
                                                  u16* __restrict__ q,
                                                  u16* __restrict__ kbuf,
                                                  u16* __restrict__ v) {
    __shared__ __align__(16) u16 As[128 * 32];
    __shared__ __align__(16) u16 Bs[128 * 32];
    f32x4 acc[4][4] = {};
    const int m0 = blockIdx.y * 128, n0 = blockIdx.x * 128;
    gemm_core<2048>(A, BT, m0, n0, acc, As, Bs);

    const int tid = threadIdx.x, wave = tid >> 6, lane = tid & 63;
    const int wr = (wave >> 1) * 64, wc = (wave & 1) * 64;
    const int t = n0 >> 11;                      // 0=q 1=k 2=v (tile fits in one region)
    u16* dst = (t == 0) ? q : (t == 1) ? kbuf : v;
#pragma unroll
    for (int m = 0; m < 4; ++m)
#pragma unroll
        for (int n = 0; n < 4; ++n)
#pragma unroll
            for (int j = 0; j < 4; ++j) {
                int gr = m0 + wr + m * 16 + (lane >> 4) * 4 + j;   // b*S+s
                int gc = n0 + wc + n * 16 + (lane & 15);           // 3*H*Dh col
                float val = acc[m][n][j] + bias[gc];
                int bb = gr >> 11, s = gr & 2047;
                int rem = gc & 2047, h = rem >> 7, d = rem & 127;
                dst[((size_t)(bb * 16 + h) * 2048 + s) * 128 + d] = f2bf(val);
            }
}

// GEMM2: out = attn@Wout + bout (fp32 output)
__global__ __launch_bounds__(256) void k_gemm_out(const u16* __restrict__ A,
                                                  const u16* __restrict__ BT,
                                                  const float* __restrict__ bias,
                                                  float* __restrict__ out) {
    __shared__ __align__(16) u16 As[128 * 32];
    __shared__ __align__(16) u16 Bs[128 * 32];
    f32x4 acc[4][4] = {};
    const int m0 = blockIdx.y * 128, n0 = blockIdx.x * 128;
    gemm_core<2048>(A, BT, m0, n0, acc, As, Bs);

    const int tid = threadIdx.x, wave = tid >> 6, lane = tid & 63;
    const int wr = (wave >> 1) * 64, wc = (wave & 1) * 64;
#pragma unroll
    for (int m = 0; m < 4; ++m)
#pragma unroll
        for (int n = 0; n < 4; ++n)
#pragma unroll
            for (int j = 0; j < 4; ++j) {
                int gr = m0 + wr + m * 16 + (lane >> 4) * 4 + j;
                int gc = n0 + wc + n * 16 + (lane & 15);
                out[(size_t)gr * 2048 + gc] = acc[m][n][j] + bias[gc];
            }
}

// ---------------- flash attention (causal), 4 waves x 16 q-rows, KVB=64 ----------------
// q,k: [B*H][S][128] bf16. vT: [B*H][128][S] bf16. o: [B][S][H*128] bf16.
__global__ __launch_bounds__(256) void k_attn(const u16* __restrict__ q,
                                              const u16* __restrict__ k,
                                              const u16* __restrict__ vT,
                                              u16* __restrict__ o) {
    __shared__ __align__(16) u16 Ks[64][136];    // K tile, +8 pad (2-way banks)
    __shared__ __align__(16) u16 Vs[128][72];    // V^T tile [d][kv], +8 pad
    __shared__ __align__(16) u16 Ps[4][16][72];  // per-wave P bounce, +8 pad
    const int head = blockIdx.y;                 // b*16+h
    const int q0 = blockIdx.x * 64;
    const int tid = threadIdx.x, wave = tid >> 6, lane = tid & 63;
    const u16* qh = q + (size_t)head * 2048 * 128;
    const u16* kh = k + (size_t)head * 2048 * 128;
    const u16* vh = vT + (size_t)head * 128 * 2048;

    bf16x8 qf[4];
    const int qr = q0 + wave * 16 + (lane & 15);
#pragma unroll
    for (int kt = 0; kt < 4; ++kt)
        qf[kt] = *(const bf16x8*)(qh + (size_t)qr * 128 + kt * 32 + (lane >> 4) * 8);

    f32x4 o_acc[8] = {};
    float m_r[4], l_r[4];
#pragma unroll
    for (int j = 0; j < 4; ++j) { m_r[j] = -1e30f; l_r[j] = 0.f; }

    const float scale = 0.08838834764831845f;    // 1/sqrt(128)
    const int kv_end = q0 + 64;
    for (int kv0 = 0; kv0 < kv_end; kv0 += 64) {
        __syncthreads();                          // all waves done with prev K/V tiles
#pragma unroll
        for (int i = 0; i < 4; ++i) {             // stage K tile 64x128
            int c = i * 256 + tid;
            int r = c >> 4, cc = (c & 15) * 8;
            *(float4*)&Ks[r][cc] = *(const float4*)(kh + (size_t)(kv0 + r) * 128 + cc);
        }
#pragma unroll
        for (int i = 0; i < 4; ++i) {             // stage V^T tile 128x64
            int c = i * 256 + tid;
            int r = c >> 3, cc = (c & 7) * 8;
            *(float4*)&Vs[r][cc] = *(const float4*)(vh + (size_t)r * 2048 + kv0 + cc);
        }
        __syncthreads();

        // S = Q K^T : D-layout row=(lane>>4)*4+j (q-local), col=c*16+(lane&15) (kv-local)
        f32x4 s_acc[4] = {};
#pragma unroll
        for (int c = 0; c < 4; ++c)
#pragma unroll
            for (int kt = 0; kt < 4; ++kt) {
                bf16x8 kb = *(const bf16x8*)&Ks[c * 16 + (lane & 15)][kt * 32 + (lane >> 4) * 8];
                s_acc[c] = MFMA(qf[kt], kb, s_acc[c]);
            }

        const bool maskblk = (kv0 + 64 > q0);     // only the diagonal block
        float alpha[4];
#pragma unroll
        for (int j = 0; j < 4; ++j) {
            int qg = q0 + wave * 16 + (lane >> 4) * 4 + j;
            float mx = -1e30f;
#pragma unroll
            for (int c = 0; c < 4; ++c) {
                float sv = s_acc[c][j] * scale;
                int kvg = kv0 + c * 16 + (lane & 15);
                if (maskblk && kvg > qg) sv = -1e30f;
                s_acc[c][j] = sv;
                mx = fmaxf(mx, sv);
            }
#pragma unroll
            for (int t = 1; t < 16; t <<= 1) mx = fmaxf(mx, __shfl_xor(mx, t));
            float mnew = fmaxf(m_r[j], mx);
            float al = __expf(m_r[j] - mnew);
            float rs = 0.f;
#pragma unroll
            for (int c = 0; c < 4; ++c) {
                float p = __expf(s_acc[c][j] - mnew);
                s_acc[c][j] = p;
                rs += p;
            }
#pragma unroll
            for (int t = 1; t < 16; t <<= 1) rs += __shfl_xor(rs, t);
            l_r[j] = l_r[j] * al + rs;
            m_r[j] = mnew;
            alpha[j] = al;
        }

        // bounce P (D-layout) -> LDS -> A-layout fragments
#pragma unroll
        for (int c = 0; c < 4; ++c)
#pragma unroll
            for (int j = 0; j < 4; ++j)
                Ps[wave][(lane >> 4) * 4 + j][c * 16 + (lane & 15)] = f2bf(s_acc[c][j]);
        __syncthreads();

        bf16x8 pf[2];
#pragma unroll
        for (int kt = 0; kt < 2; ++kt)
            pf[kt] = *(const bf16x8*)&Ps[wave][lane & 15][kt * 32 + (lane >> 4) * 8];
#pragma unroll
        for (int c2 = 0; c2 < 8; ++c2) {
#pragma unroll
            for (int j = 0; j < 4; ++j) o_acc[c2][j] *= alpha[j];
#pragma unroll
            for (int kt = 0; kt < 2; ++kt) {
                bf16x8 vf = *(const bf16x8*)&Vs[c2 * 16 + (lane & 15)][kt * 32 + (lane >> 4) * 8];
                o_acc[c2] = MFMA(pf[kt], vf, o_acc[c2]);
            }
        }
    }

    const int bb = head >> 4, hh = head & 15;
#pragma unroll
    for (int c2 = 0; c2 < 8; ++c2)
#pragma unroll
        for (int j = 0; j < 4; ++j) {
            int qg = q0 + wave * 16 + (lane >> 4) * 4 + j;
            int d = c2 * 16 + (lane & 15);
            float val = o_acc[c2][j] / l_r[j];
            o[((size_t)(bb * 2048 + qg)) * 2048 + hh * 128 + d] = f2bf(val);
        }
}

// ---------------- launcher ----------------

extern "C" void kernel_launch(void* const* d_in, const int* in_sizes, int n_in,
                              void* d_out, int out_size, void* d_ws, size_t ws_size,
                              hipStream_t stream) {
    const float* x    = (const float*)d_in[0];   // [2,2048,2048]
    const float* Wqkv = (const float*)d_in[1];   // [2048,6144]
    const float* bqkv = (const float*)d_in[2];   // [6144]
    const float* Wout = (const float*)d_in[3];   // [2048,2048]
    const float* bout = (const float*)d_in[4];   // [2048]
    float* out = (float*)d_out;                  // [2,2048,2048] fp32

    char* ws = (char*)d_ws;
    const size_t SZ = 16777216;                  // 16 MiB units
    u16* q   = (u16*)(ws);                       // [32][2048][128] bf16
    u16* kb  = (u16*)(ws + SZ);                  // same
    u16* v   = (u16*)(ws + 2 * SZ);              // same (dead after transpose)
    u16* vT  = (u16*)(ws + 3 * SZ);              // [32][128][2048] bf16
    u16* ao  = v;                                // attn output reuses v region
    u16* xb  = (u16*)(ws + 4 * SZ);              // x bf16 [4096][2048]
    u16* WqT = (u16*)(ws + 5 * SZ);              // Wqkv^T bf16 [6144][2048]
    u16* WoT = (u16*)(ws + 5 * SZ + 25165824);   // Wout^T bf16 [2048][2048]
    // total ws use: ~112 MiB

    k_cast<<<dim3(8192), dim3(256), 0, stream>>>(x, xb, 2097152);
    k_castT<<<dim3(192, 64), dim3(32, 8), 0, stream>>>(Wqkv, WqT, 2048, 6144);
    k_castT<<<dim3(64, 64), dim3(32, 8), 0, stream>>>(Wout, WoT, 2048, 2048);
    k_gemm_qkv<<<dim3(48, 32), dim3(256), 0, stream>>>(xb, WqT, bqkv, q, kb, v);
    k_transv<<<dim3(64, 4, 32), dim3(32, 8), 0, stream>>>(v, vT);
    k_attn<<<dim3(32, 32), dim3(256), 0, stream>>>(q, kb, vT, ao);
    k_gemm_out<<<dim3(16, 32), dim3(256), 0, stream>>>(ao, WoT, bout, out);
}

// Round 2
// 371.988 us; speedup vs baseline: 1.2932x; 1.2932x over previous
//
#include <hip/hip_runtime.h>

// Fused causal attention block: qkv = x@Wqkv+b; flash-attn(causal); out = attn@Wout+b
// B=2, S=2048, D=2048, H=16, Dh=128. All GEMM/attn compute in bf16 MFMA, fp32 accum.

typedef unsigned short u16;
typedef __attribute__((ext_vector_type(8))) short bf16x8;   // 8 bf16 (4 VGPRs)
typedef __attribute__((ext_vector_type(4))) float f32x4;

#define MFMA(a, b, c) __builtin_amdgcn_mfma_f32_16x16x32_bf16((a), (b), (c), 0, 0, 0)

__device__ __forceinline__ u16 f2bf(float f) {           // RNE fp32->bf16
    unsigned u = __builtin_bit_cast(unsigned, f);
    u += 0x7fffu + ((u >> 16) & 1u);
    return (u16)(u >> 16);
}

__device__ __forceinline__ void gload16(const void* g, void* l) {
    __builtin_amdgcn_global_load_lds(
        (const __attribute__((address_space(1))) void*)g,
        (__attribute__((address_space(3))) void*)l, 16, 0, 0);
}

// ---------------- cast / transpose helpers ----------------

__global__ __launch_bounds__(256) void k_cast(const float* __restrict__ src,
                                              u16* __restrict__ dst, int n4) {
    int i = blockIdx.x * 256 + threadIdx.x;
    if (i >= n4) return;
    float4 a = ((const float4*)src)[i];
    ushort4 r;
    r.x = f2bf(a.x); r.y = f2bf(a.y); r.z = f2bf(a.z); r.w = f2bf(a.w);
    ((ushort4*)dst)[i] = r;
}

// src [rows][cols] fp32 -> dst [cols][rows] bf16
__global__ __launch_bounds__(256) void k_castT(const float* __restrict__ src,
                                               u16* __restrict__ dst, int rows, int cols) {
    __shared__ float t[32][33];
    int c0 = blockIdx.x * 32, r0 = blockIdx.y * 32;
    int tx = threadIdx.x, ty = threadIdx.y;
#pragma unroll
    for (int i = 0; i < 4; ++i)
        t[ty + 8 * i][tx] = src[(size_t)(r0 + ty + 8 * i) * cols + (c0 + tx)];
    __syncthreads();
#pragma unroll
    for (int i = 0; i < 4; ++i)
        dst[(size_t)(c0 + ty + 8 * i) * rows + (r0 + tx)] = f2bf(t[tx][ty + 8 * i]);
}

// v [head][2048][128] bf16 -> vT [head][128][2048] bf16
__global__ __launch_bounds__(256) void k_transv(const u16* __restrict__ v,
                                                u16* __restrict__ vT) {
    __shared__ u16 t[32][33];
    int head = blockIdx.z;
    int s0 = blockIdx.x * 32, d0 = blockIdx.y * 32;
    const u16* vp = v + (size_t)head * 2048 * 128;
    u16* op = vT + (size_t)head * 128 * 2048;
    int tx = threadIdx.x, ty = threadIdx.y;
#pragma unroll
    for (int i = 0; i < 4; ++i)
        t[ty + 8 * i][tx] = vp[(size_t)(s0 + ty + 8 * i) * 128 + d0 + tx];
    __syncthreads();
#pragma unroll
    for (int i = 0; i < 4; ++i)
        op[(size_t)(d0 + ty + 8 * i) * 2048 + (s0 + tx)] = t[tx][ty + 8 * i];
}

// ---------------- GEMM core (m97 structure): C[128x128] tile, BK=32 ----------------
// A [M][K] bf16 row-major; BT [N][K] bf16 row-major (i.e. B transposed).

template <int K>
__device__ __forceinline__ void gemm_core(const u16* __restrict__ A,
                                          const u16* __restrict__ BT,
                                          int m0, int n0,
                                          f32x4 (&acc)[4][4],
                                          u16* As, u16* Bs) {
    const int tid = threadIdx.x, wave = tid >> 6, lane = tid & 63;
    const int wr = (wave >> 1) * 64, wc = (wave & 1) * 64;
    for (int k0 = 0; k0 < K; k0 += 32) {
        __syncthreads();   // previous compute done before LDS overwrite
#pragma unroll
        for (int i = 0; i < 2; ++i) {
            int cb = (i * 4 + wave) * 64;         // wave-uniform chunk base
            int c = cb + lane;
            int row = c >> 2, kk = (c & 3) * 8;   // 4 x 16B chunks per 32-elem row
            gload16(A + (size_t)(m0 + row) * K + k0 + kk, As + cb * 8);
            gload16(BT + (size_t)(n0 + row) * K + k0 + kk, Bs + cb * 8);
        }
        __syncthreads();   // vmcnt(0) drain before reads
        bf16x8 a[4], b[4];
#pragma unroll
        for (int m = 0; m < 4; ++m)
            a[m] = *(const bf16x8*)(As + (wr + m * 16 + (lane & 15)) * 32 + (lane >> 4) * 8);
#pragma unroll
        for (int n = 0; n < 4; ++n)
            b[n] = *(const bf16x8*)(Bs + (wc + n * 16 + (lane & 15)) * 32 + (lane >> 4) * 8);
#pragma unroll
        for (int m = 0; m < 4; ++m)
#pragma unroll
            for (int n = 0; n < 4; ++n)
                acc[m][n] = MFMA(a[m], b[n], acc[m][n]);
    }
}

// GEMM1: qkv = x@Wqkv + bqkv, scattered into q/k/v [B*H][S][Dh] bf16
__global__ __launch_bounds__(256) void k_gemm_qkv(const u16* __restrict__ A,
                                                  const u16* __restrict__ BT,
                                                  const float* __restrict__ bias,
                                                  u16* __restrict__ q,
                                                  u16* __restrict__ kbuf,
                                                  u16* __restrict__ v) {
    __shared__ __align__(16) u16 As[128 * 32];
    __shared__ __align__(16) u16 Bs[128 * 32];
    f32x4 acc[4][4] = {};
    const int m0 = blockIdx.y * 128, n0 = blockIdx.x * 128;
    gemm_core<2048>(A, BT, m0, n0, acc, As, Bs);

    const int tid = threadIdx.x, wave = tid >> 6, lane = tid & 63;
    const int wr = (wave >> 1) * 64, wc = (wave & 1) * 64;
    const int t = n0 >> 11;                      // 0=q 1=k 2=v (tile fits in one region)
    u16* dst = (t == 0) ? q : (t == 1) ? kbuf : v;
#pragma unroll
    for (int m = 0; m < 4; ++m)
#pragma unroll
        for (int n = 0; n < 4; ++n)
#pragma unroll
            for (int j = 0; j < 4; ++j) {
                int gr = m0 + wr + m * 16 + (lane >> 4) * 4 + j;   // b*S+s
                int gc = n0 + wc + n * 16 + (lane & 15);           // 3*H*Dh col
                float val = acc[m][n][j] + bias[gc];
                int bb = gr >> 11, s = gr & 2047;
                int rem = gc & 2047, h = rem >> 7, d = rem & 127;
                dst[((size_t)(bb * 16 + h) * 2048 + s) * 128 + d] = f2bf(val);
            }
}

// GEMM2: out = attn@Wout + bout (fp32 output)
__global__ __launch_bounds__(256) void k_gemm_out(const u16* __restrict__ A,
                                                  const u16* __restrict__ BT,
                                                  const float* __restrict__ bias,
                                                  float* __restrict__ out) {
    __shared__ __align__(16) u16 As[128 * 32];
    __shared__ __align__(16) u16 Bs[128 * 32];
    f32x4 acc[4][4] = {};
    const int m0 = blockIdx.y * 128, n0 = blockIdx.x * 128;
    gemm_core<2048>(A, BT, m0, n0, acc, As, Bs);

    const int tid = threadIdx.x, wave = tid >> 6, lane = tid & 63;
    const int wr = (wave >> 1) * 64, wc = (wave & 1) * 64;
#pragma unroll
    for (int m = 0; m < 4; ++m)
#pragma unroll
        for (int n = 0; n < 4; ++n)
#pragma unroll
            for (int j = 0; j < 4; ++j) {
                int gr = m0 + wr + m * 16 + (lane >> 4) * 4 + j;
                int gc = n0 + wc + n * 16 + (lane & 15);
                out[(size_t)gr * 2048 + gc] = acc[m][n][j] + bias[gc];
            }
}

// ---------------- flash attention (causal) v2 ----------------
// 4 waves x 16 q-rows, KVB=64, causal PAIR scheduling: block handles q-tiles
// {pair, 31-pair} -> 33 kv-tiles each (balanced). Reg-staged K/V prefetch
// (T14), XOR-swizzled LDS (byte ^= (row&7)<<4), exp2-domain online softmax.
// q,k: [B*H][S][128] bf16. vT: [B*H][128][S] bf16. o: [B][S][H*128] bf16.
__global__ __launch_bounds__(256) void k_attn(const u16* __restrict__ q,
                                              const u16* __restrict__ k,
                                              const u16* __restrict__ vT,
                                              u16* __restrict__ o) {
    __shared__ __align__(16) u16 KsA[64 * 128];      // 16 KB, rows 256 B
    __shared__ __align__(16) u16 VsA[128 * 64];      // 16 KB, rows 128 B (V^T: [d][kv])
    __shared__ __align__(16) u16 PsA[4 * 16 * 64];   // 8 KB, per-wave 16x64, rows 128 B
    char* ksB = (char*)KsA;
    char* vsB = (char*)VsA;

    const int tid = threadIdx.x, wave = tid >> 6, lane = tid & 63;
    char* psB = (char*)PsA + wave * 2048;

    // XCD-chunked remap: 512 blocks, 8 XCDs, 64 consecutive work items per XCD
    // -> each XCD owns 4 heads (K/V stay L2-local).
    const int lin = blockIdx.y * 16 + blockIdx.x;
    const int dd = (lin & 7) * 64 + (lin >> 3);
    const int head = dd >> 4, pair = dd & 15;

    const u16* qh = q + (size_t)head * 2048 * 128;
    const u16* kh = k + (size_t)head * 2048 * 128;
    const u16* vh = vT + (size_t)head * 128 * 2048;
    const int bb = head >> 4, hh = head & 15;
    const float qscale = 0.1275293562566334f;        // (1/sqrt(128)) * log2(e)

#pragma unroll 1
    for (int qsel = 0; qsel < 2; ++qsel) {
        const int qi = qsel ? (31 - pair) : pair;
        const int q0 = qi * 64;
        const int ntile = qi + 1;

        bf16x8 qf[4];
        const int qr = q0 + wave * 16 + (lane & 15);
#pragma unroll
        for (int kt = 0; kt < 4; ++kt)
            qf[kt] = *(const bf16x8*)(qh + (size_t)qr * 128 + kt * 32 + (lane >> 4) * 8);

        f32x4 o_acc[8] = {};
        float m_r[4], l_r[4];
#pragma unroll
        for (int j = 0; j < 4; ++j) { m_r[j] = -1e30f; l_r[j] = 0.f; }

        // prefetch tile 0 into registers
        float4 kreg[4], vreg[4];
#pragma unroll
        for (int i = 0; i < 4; ++i) {
            int id = i * 256 + tid;
            kreg[i] = *(const float4*)(kh + (size_t)(id >> 4) * 128 + (id & 15) * 8);
            vreg[i] = *(const float4*)(vh + (size_t)(id >> 3) * 2048 + (id & 7) * 8);
        }

        for (int t = 0; t < ntile; ++t) {
            const int kv0 = t * 64;
            __syncthreads();                          // prev tile's LDS reads done
            // regs -> LDS (swizzled); compiler waits vmcnt for kreg/vreg here
#pragma unroll
            for (int i = 0; i < 4; ++i) {
                int id = i * 256 + tid;
                int kr = id >> 4, kc = (id & 15) * 16;
                *(float4*)(ksB + ((kr * 256 + kc) ^ ((kr & 7) << 4))) = kreg[i];
                int vr = id >> 3, vc = (id & 7) * 16;
                *(float4*)(vsB + ((vr * 128 + vc) ^ ((vr & 7) << 4))) = vreg[i];
            }
            if (t + 1 < ntile) {                      // issue next tile early (T14)
                const int kv1 = kv0 + 64;
#pragma unroll
                for (int i = 0; i < 4; ++i) {
                    int id = i * 256 + tid;
                    kreg[i] = *(const float4*)(kh + (size_t)(kv1 + (id >> 4)) * 128 + (id & 15) * 8);
                    vreg[i] = *(const float4*)(vh + (size_t)(id >> 3) * 2048 + kv1 + (id & 7) * 8);
                }
            }
            __syncthreads();                          // LDS tile ready

            // S = Q K^T : D-layout row=(lane>>4)*4+j (q-local), col=c*16+(lane&15) (kv-local)
            f32x4 s_acc[4] = {};
#pragma unroll
            for (int c = 0; c < 4; ++c) {
                int row = c * 16 + (lane & 15);
#pragma unroll
                for (int kt = 0; kt < 4; ++kt) {
                    bf16x8 kb = *(const bf16x8*)(ksB +
                        ((row * 256 + kt * 64 + (lane >> 4) * 16) ^ ((row & 7) << 4)));
                    s_acc[c] = MFMA(qf[kt], kb, s_acc[c]);
                }
            }

            const bool maskblk = (kv0 + 64 > q0);     // only the diagonal block
            float alpha[4];
#pragma unroll
            for (int j = 0; j < 4; ++j) {
                int qg = q0 + wave * 16 + (lane >> 4) * 4 + j;
                float mx = -1e30f;
#pragma unroll
                for (int c = 0; c < 4; ++c) {
                    float sv = s_acc[c][j] * qscale;   // log2 domain
                    if (maskblk && (kv0 + c * 16 + (lane & 15)) > qg) sv = -1e30f;
                    s_acc[c][j] = sv;
                    mx = fmaxf(mx, sv);
                }
#pragma unroll
                for (int t2 = 1; t2 < 16; t2 <<= 1) mx = fmaxf(mx, __shfl_xor(mx, t2));
                float mnew = fmaxf(m_r[j], mx);
                alpha[j] = exp2f(m_r[j] - mnew);
                float rs = 0.f;
#pragma unroll
                for (int c = 0; c < 4; ++c) {
                    float p = exp2f(s_acc[c][j] - mnew);
                    s_acc[c][j] = p;
                    rs += p;
                }
#pragma unroll
                for (int t2 = 1; t2 < 16; t2 <<= 1) rs += __shfl_xor(rs, t2);
                l_r[j] = l_r[j] * alpha[j] + rs;
                m_r[j] = mnew;
            }

            // bounce P (D-layout) -> per-wave LDS -> A-layout fragments (no barrier)
#pragma unroll
            for (int c = 0; c < 4; ++c)
#pragma unroll
                for (int j = 0; j < 4; ++j) {
                    int row = (lane >> 4) * 4 + j;
                    *(u16*)(psB + ((row * 128 + (c * 16 + (lane & 15)) * 2) ^ ((row & 7) << 4)))
                        = f2bf(s_acc[c][j]);
                }
            bf16x8 pf[2];
#pragma unroll
            for (int kt = 0; kt < 2; ++kt) {
                int row2 = lane & 15;
                pf[kt] = *(const bf16x8*)(psB +
                    ((row2 * 128 + kt * 64 + (lane >> 4) * 16) ^ ((row2 & 7) << 4)));
            }
#pragma unroll
            for (int c2 = 0; c2 < 8; ++c2) {
#pragma unroll
                for (int j = 0; j < 4; ++j) o_acc[c2][j] *= alpha[j];
#pragma unroll
                for (int kt = 0; kt < 2; ++kt) {
                    int row = c2 * 16 + (lane & 15);
                    bf16x8 vf = *(const bf16x8*)(vsB +
                        ((row * 128 + kt * 64 + (lane >> 4) * 16) ^ ((row & 7) << 4)));
                    o_acc[c2] = MFMA(pf[kt], vf, o_acc[c2]);
                }
            }
        }

        float linv[4];
#pragma unroll
        for (int j = 0; j < 4; ++j) linv[j] = 1.0f / l_r[j];
#pragma unroll
        for (int c2 = 0; c2 < 8; ++c2)
#pragma unroll
            for (int j = 0; j < 4; ++j) {
                int qg = q0 + wave * 16 + (lane >> 4) * 4 + j;
                int d2 = c2 * 16 + (lane & 15);
                o[((size_t)(bb * 2048 + qg)) * 2048 + hh * 128 + d2]
                    = f2bf(o_acc[c2][j] * linv[j]);
            }
    }
}

// ---------------- launcher ----------------

extern "C" void kernel_launch(void* const* d_in, const int* in_sizes, int n_in,
                              void* d_out, int out_size, void* d_ws, size_t ws_size,
                              hipStream_t stream) {
    const float* x    = (const float*)d_in[0];   // [2,2048,2048]
    const float* Wqkv = (const float*)d_in[1];   // [2048,6144]
    const float* bqkv = (const float*)d_in[2];   // [6144]
    const float* Wout = (const float*)d_in[3];   // [2048,2048]
    const float* bout = (const float*)d_in[4];   // [2048]
    float* out = (float*)d_out;                  // [2,2048,2048] fp32

    char* ws = (char*)d_ws;
    const size_t SZ = 16777216;                  // 16 MiB units
    u16* q   = (u16*)(ws);                       // [32][2048][128] bf16
    u16* kb  = (u16*)(ws + SZ);                  // same
    u16* v   = (u16*)(ws + 2 * SZ);              // same (dead after transpose)
    u16* vT  = (u16*)(ws + 3 * SZ);              // [32][128][2048] bf16
    u16* ao  = v;                                // attn output reuses v region
    u16* xb  = (u16*)(ws + 4 * SZ);              // x bf16 [4096][2048]
    u16* WqT = (u16*)(ws + 5 * SZ);              // Wqkv^T bf16 [6144][2048]
    u16* WoT = (u16*)(ws + 5 * SZ + 25165824);   // Wout^T bf16 [2048][2048]
    // total ws use: ~112 MiB

    k_cast<<<dim3(8192), dim3(256), 0, stream>>>(x, xb, 2097152);
    k_castT<<<dim3(192, 64), dim3(32, 8), 0, stream>>>(Wqkv, WqT, 2048, 6144);
    k_castT<<<dim3(64, 64), dim3(32, 8), 0, stream>>>(Wout, WoT, 2048, 2048);
    k_gemm_qkv<<<dim3(48, 32), dim3(256), 0, stream>>>(xb, WqT, bqkv, q, kb, v);
    k_transv<<<dim3(64, 4, 32), dim3(32, 8), 0, stream>>>(v, vT);
    k_attn<<<dim3(16, 32), dim3(256), 0, stream>>>(q, kb, vT, ao);
    k_gemm_out<<<dim3(16, 32), dim3(256), 0, stream>>>(ao, WoT, bout, out);
}

// Round 3
// 352.977 us; speedup vs baseline: 1.3628x; 1.0539x over previous
//
#include <hip/hip_runtime.h>

// Fused causal attention block: qkv = x@Wqkv+b; flash-attn(causal); out = attn@Wout+b
// B=2, S=2048, D=2048, H=16, Dh=128. All GEMM/attn compute in bf16 MFMA, fp32 accum.

typedef unsigned short u16;
typedef __attribute__((ext_vector_type(8))) short bf16x8;   // 8 bf16 (4 VGPRs)
typedef __attribute__((ext_vector_type(4))) float f32x4;

#define MFMA(a, b, c) __builtin_amdgcn_mfma_f32_16x16x32_bf16((a), (b), (c), 0, 0, 0)

__device__ __forceinline__ u16 f2bf(float f) {           // RNE fp32->bf16
    unsigned u = __builtin_bit_cast(unsigned, f);
    u += 0x7fffu + ((u >> 16) & 1u);
    return (u16)(u >> 16);
}

__device__ __forceinline__ void gload16(const void* g, void* l) {
    __builtin_amdgcn_global_load_lds(
        (const __attribute__((address_space(1))) void*)g,
        (__attribute__((address_space(3))) void*)l, 16, 0, 0);
}

// ---------------- cast / transpose helpers ----------------

__global__ __launch_bounds__(256) void k_cast(const float* __restrict__ src,
                                              u16* __restrict__ dst, int n4) {
    int i = blockIdx.x * 256 + threadIdx.x;
    if (i >= n4) return;
    float4 a = ((const float4*)src)[i];
    ushort4 r;
    r.x = f2bf(a.x); r.y = f2bf(a.y); r.z = f2bf(a.z); r.w = f2bf(a.w);
    ((ushort4*)dst)[i] = r;
}

// src [rows][cols] fp32 -> dst [cols][rows] bf16
__global__ __launch_bounds__(256) void k_castT(const float* __restrict__ src,
                                               u16* __restrict__ dst, int rows, int cols) {
    __shared__ float t[32][33];
    int c0 = blockIdx.x * 32, r0 = blockIdx.y * 32;
    int tx = threadIdx.x, ty = threadIdx.y;
#pragma unroll
    for (int i = 0; i < 4; ++i)
        t[ty + 8 * i][tx] = src[(size_t)(r0 + ty + 8 * i) * cols + (c0 + tx)];
    __syncthreads();
#pragma unroll
    for (int i = 0; i < 4; ++i)
        dst[(size_t)(c0 + ty + 8 * i) * rows + (r0 + tx)] = f2bf(t[tx][ty + 8 * i]);
}

// v [head][2048][128] bf16 -> vT [head][128][2048] bf16
__global__ __launch_bounds__(256) void k_transv(const u16* __restrict__ v,
                                                u16* __restrict__ vT) {
    __shared__ u16 t[32][33];
    int head = blockIdx.z;
    int s0 = blockIdx.x * 32, d0 = blockIdx.y * 32;
    const u16* vp = v + (size_t)head * 2048 * 128;
    u16* op = vT + (size_t)head * 128 * 2048;
    int tx = threadIdx.x, ty = threadIdx.y;
#pragma unroll
    for (int i = 0; i < 4; ++i)
        t[ty + 8 * i][tx] = vp[(size_t)(s0 + ty + 8 * i) * 128 + d0 + tx];
    __syncthreads();
#pragma unroll
    for (int i = 0; i < 4; ++i)
        op[(size_t)(d0 + ty + 8 * i) * 2048 + (s0 + tx)] = t[tx][ty + 8 * i];
}

// ---------------- GEMM core (m97 structure): C[128x128] tile, BK=32 ----------------
// A [M][K] bf16 row-major; BT [N][K] bf16 row-major (i.e. B transposed).

template <int K>
__device__ __forceinline__ void gemm_core(const u16* __restrict__ A,
                                          const u16* __restrict__ BT,
                                          int m0, int n0,
                                          f32x4 (&acc)[4][4],
                                          u16* As, u16* Bs) {
    const int tid = threadIdx.x, wave = tid >> 6, lane = tid & 63;
    const int wr = (wave >> 1) * 64, wc = (wave & 1) * 64;
    for (int k0 = 0; k0 < K; k0 += 32) {
        __syncthreads();   // previous compute done before LDS overwrite
#pragma unroll
        for (int i = 0; i < 2; ++i) {
            int cb = (i * 4 + wave) * 64;         // wave-uniform chunk base
            int c = cb + lane;
            int row = c >> 2, kk = (c & 3) * 8;   // 4 x 16B chunks per 32-elem row
            gload16(A + (size_t)(m0 + row) * K + k0 + kk, As + cb * 8);
            gload16(BT + (size_t)(n0 + row) * K + k0 + kk, Bs + cb * 8);
        }
        __syncthreads();   // vmcnt(0) drain before reads
        bf16x8 a[4], b[4];
#pragma unroll
        for (int m = 0; m < 4; ++m)
            a[m] = *(const bf16x8*)(As + (wr + m * 16 + (lane & 15)) * 32 + (lane >> 4) * 8);
#pragma unroll
        for (int n = 0; n < 4; ++n)
            b[n] = *(const bf16x8*)(Bs + (wc + n * 16 + (lane & 15)) * 32 + (lane >> 4) * 8);
        __builtin_amdgcn_s_setprio(1);
#pragma unroll
        for (int m = 0; m < 4; ++m)
#pragma unroll
            for (int n = 0; n < 4; ++n)
                acc[m][n] = MFMA(a[m], b[n], acc[m][n]);
        __builtin_amdgcn_s_setprio(0);
    }
}

// GEMM1: qkv = x@Wqkv + bqkv, scattered into q/k/v [B*H][S][Dh] bf16
__global__ __launch_bounds__(256) void k_gemm_qkv(const u16* __restrict__ A,
                                                  const u16* __restrict__ BT,
                                                  const float* __restrict__ bias,
                                                  u16* __restrict__ q,
                                                  u16* __restrict__ kbuf,
                                                  u16* __restrict__ v) {
    __shared__ __align__(16) u16 As[128 * 32];
    __shared__ __align__(16) u16 Bs[128 * 32];
    f32x4 acc[4][4] = {};
    // XCD-chunked remap (nwg = 48*32 = 1536, %8 == 0 -> simple bijection)
    const int orig = blockIdx.y * 48 + blockIdx.x;
    const int nb = (orig & 7) * 192 + (orig >> 3);
    const int m0 = (nb / 48) * 128, n0 = (nb % 48) * 128;
    gemm_core<2048>(A, BT, m0, n0, acc, As, Bs);

    const int tid = threadIdx.x, wave = tid >> 6, lane = tid & 63;
    const int wr = (wave >> 1) * 64, wc = (wave & 1) * 64;
    const int t = n0 >> 11;                      // 0=q 1=k 2=v (tile fits in one region)
    u16* dst = (t == 0) ? q : (t == 1) ? kbuf : v;
#pragma unroll
    for (int m = 0; m < 4; ++m)
#pragma unroll
        for (int n = 0; n < 4; ++n)
#pragma unroll
            for (int j = 0; j < 4; ++j) {
                int gr = m0 + wr + m * 16 + (lane >> 4) * 4 + j;   // b*S+s
                int gc = n0 + wc + n * 16 + (lane & 15);           // 3*H*Dh col
                float val = acc[m][n][j] + bias[gc];
                int bb = gr >> 11, s = gr & 2047;
                int rem = gc & 2047, h = rem >> 7, d = rem & 127;
                dst[((size_t)(bb * 16 + h) * 2048 + s) * 128 + d] = f2bf(val);
            }
}

// GEMM2: out = attn@Wout + bout (fp32 output)
__global__ __launch_bounds__(256) void k_gemm_out(const u16* __restrict__ A,
                                                  const u16* __restrict__ BT,
                                                  const float* __restrict__ bias,
                                                  float* __restrict__ out) {
    __shared__ __align__(16) u16 As[128 * 32];
    __shared__ __align__(16) u16 Bs[128 * 32];
    f32x4 acc[4][4] = {};
    // XCD-chunked remap (nwg = 16*32 = 512)
    const int orig = blockIdx.y * 16 + blockIdx.x;
    const int nb = (orig & 7) * 64 + (orig >> 3);
    const int m0 = (nb / 16) * 128, n0 = (nb % 16) * 128;
    gemm_core<2048>(A, BT, m0, n0, acc, As, Bs);

    const int tid = threadIdx.x, wave = tid >> 6, lane = tid & 63;
    const int wr = (wave >> 1) * 64, wc = (wave & 1) * 64;
#pragma unroll
    for (int m = 0; m < 4; ++m)
#pragma unroll
        for (int n = 0; n < 4; ++n)
#pragma unroll
            for (int j = 0; j < 4; ++j) {
                int gr = m0 + wr + m * 16 + (lane >> 4) * 4 + j;
                int gc = n0 + wc + n * 16 + (lane & 15);
                out[(size_t)gr * 2048 + gc] = acc[m][n][j] + bias[gc];
            }
}

// ---------------- flash attention (causal) v3 ----------------
// 1024 blocks, one 64-row q-tile each; 4 waves x 16 q-rows; KVB=64.
// K/V staged via global_load_lds (no VGPR staging -> no spills) with
// PRE-SWIZZLED global source (linear LDS dest, XOR applied on reads).
// XCD-chunked remap: each XCD owns 4 heads (K/V L2-resident).
// q,k: [B*H][S][128] bf16. vT: [B*H][128][S] bf16. o: [B][S][H*128] bf16.
__global__ __launch_bounds__(256) void k_attn(const u16* __restrict__ q,
                                              const u16* __restrict__ k,
                                              const u16* __restrict__ vT,
                                              u16* __restrict__ o) {
    __shared__ __align__(16) u16 KsA[64 * 128];      // 16 KB, rows 256 B
    __shared__ __align__(16) u16 VsA[128 * 64];      // 16 KB, rows 128 B (V^T: [d][kv])
    __shared__ __align__(16) u16 PsA[4 * 16 * 64];   // 8 KB, per-wave 16x64, rows 128 B
    char* ksB = (char*)KsA;
    char* vsB = (char*)VsA;

    const int tid = threadIdx.x, wave = tid >> 6, lane = tid & 63;
    char* psB = (char*)PsA + wave * 2048;

    // hardware round-robins consecutive blockIdx across 8 XCDs; this remap
    // gives each XCD a contiguous 128-chunk of work = 4 heads x 32 q-tiles.
    const int lin = blockIdx.x;
    const int dd = (lin & 7) * 128 + (lin >> 3);
    const int head = dd >> 5, qi = dd & 31;
    const int q0 = qi * 64, ntile = qi + 1;

    const u16* qh = q + (size_t)head * 2048 * 128;
    const u16* kh = k + (size_t)head * 2048 * 128;
    const u16* vh = vT + (size_t)head * 128 * 2048;
    const int bb = head >> 4, hh = head & 15;
    const float qscale = 0.1275293562566334f;        // (1/sqrt(128)) * log2(e)

    bf16x8 qf[4];
    const int qr = q0 + wave * 16 + (lane & 15);
#pragma unroll
    for (int kt = 0; kt < 4; ++kt)
        qf[kt] = *(const bf16x8*)(qh + (size_t)qr * 128 + kt * 32 + (lane >> 4) * 8);

    f32x4 o_acc[8] = {};
    float m_r[4], l_r[4];
#pragma unroll
    for (int j = 0; j < 4; ++j) { m_r[j] = -1e30f; l_r[j] = 0.f; }

    for (int t = 0; t < ntile; ++t) {
        const int kv0 = t * 64;
        __syncthreads();                          // prev tile's LDS reads done
        // stage K tile 64x128 (1024 16B chunks): linear LDS dest, source
        // address pre-swizzled so the LDS image is XOR-swizzled.
#pragma unroll
        for (int i = 0; i < 4; ++i) {
            int cb = (i * 4 + wave) * 64;         // wave-uniform chunk base
            int d = (cb + lane) * 16;             // dest byte offset
            int r = d >> 8;                       // K row
            int co = (d & 255) ^ ((r & 7) << 4);  // swizzled col byte
            gload16(kh + (size_t)(kv0 + r) * 128 + (co >> 1), ksB + cb * 16);
        }
#pragma unroll
        for (int i = 0; i < 4; ++i) {             // stage V^T tile 128x64
            int cb = (i * 4 + wave) * 64;
            int d = (cb + lane) * 16;
            int vr = d >> 7;                      // V^T row (d-dim)
            int co = (d & 127) ^ ((vr & 7) << 4);
            gload16(vh + (size_t)vr * 2048 + kv0 + (co >> 1), vsB + cb * 16);
        }
        __syncthreads();                          // drain, tile ready

        // S = Q K^T : D-layout row=(lane>>4)*4+j (q-local), col=c*16+(lane&15)
        f32x4 s_acc[4] = {};
        __builtin_amdgcn_s_setprio(1);
#pragma unroll
        for (int c = 0; c < 4; ++c) {
            int row = c * 16 + (lane & 15);
#pragma unroll
            for (int kt = 0; kt < 4; ++kt) {
                bf16x8 kb = *(const bf16x8*)(ksB +
                    ((row * 256 + kt * 64 + (lane >> 4) * 16) ^ ((row & 7) << 4)));
                s_acc[c] = MFMA(qf[kt], kb, s_acc[c]);
            }
        }
        __builtin_amdgcn_s_setprio(0);

        const bool maskblk = (kv0 + 64 > q0);     // only the diagonal block
        float alpha[4];
#pragma unroll
        for (int j = 0; j < 4; ++j) {
            int qg = q0 + wave * 16 + (lane >> 4) * 4 + j;
            float mx = -1e30f;
#pragma unroll
            for (int c = 0; c < 4; ++c) {
                float sv = s_acc[c][j] * qscale;   // log2 domain
                if (maskblk && (kv0 + c * 16 + (lane & 15)) > qg) sv = -1e30f;
                s_acc[c][j] = sv;
                mx = fmaxf(mx, sv);
            }
#pragma unroll
            for (int t2 = 1; t2 < 16; t2 <<= 1) mx = fmaxf(mx, __shfl_xor(mx, t2));
            float mnew = fmaxf(m_r[j], mx);
            alpha[j] = exp2f(m_r[j] - mnew);
            float rs = 0.f;
#pragma unroll
            for (int c = 0; c < 4; ++c) {
                float p = exp2f(s_acc[c][j] - mnew);
                s_acc[c][j] = p;
                rs += p;
            }
#pragma unroll
            for (int t2 = 1; t2 < 16; t2 <<= 1) rs += __shfl_xor(rs, t2);
            l_r[j] = l_r[j] * alpha[j] + rs;
            m_r[j] = mnew;
        }

        // bounce P (D-layout) -> per-wave LDS -> A-layout fragments (no barrier)
#pragma unroll
        for (int c = 0; c < 4; ++c)
#pragma unroll
            for (int j = 0; j < 4; ++j) {
                int row = (lane >> 4) * 4 + j;
                *(u16*)(psB + ((row * 128 + (c * 16 + (lane & 15)) * 2) ^ ((row & 7) << 4)))
                    = f2bf(s_acc[c][j]);
            }
        bf16x8 pf[2];
#pragma unroll
        for (int kt = 0; kt < 2; ++kt) {
            int row2 = lane & 15;
            pf[kt] = *(const bf16x8*)(psB +
                ((row2 * 128 + kt * 64 + (lane >> 4) * 16) ^ ((row2 & 7) << 4)));
        }
        __builtin_amdgcn_s_setprio(1);
#pragma unroll
        for (int c2 = 0; c2 < 8; ++c2) {
#pragma unroll
            for (int j = 0; j < 4; ++j) o_acc[c2][j] *= alpha[j];
#pragma unroll
            for (int kt = 0; kt < 2; ++kt) {
                int row = c2 * 16 + (lane & 15);
                bf16x8 vf = *(const bf16x8*)(vsB +
                    ((row * 128 + kt * 64 + (lane >> 4) * 16) ^ ((row & 7) << 4)));
                o_acc[c2] = MFMA(pf[kt], vf, o_acc[c2]);
            }
        }
        __builtin_amdgcn_s_setprio(0);
    }

    float linv[4];
#pragma unroll
    for (int j = 0; j < 4; ++j) linv[j] = 1.0f / l_r[j];
#pragma unroll
    for (int c2 = 0; c2 < 8; ++c2)
#pragma unroll
        for (int j = 0; j < 4; ++j) {
            int qg = q0 + wave * 16 + (lane >> 4) * 4 + j;
            int d2 = c2 * 16 + (lane & 15);
            o[((size_t)(bb * 2048 + qg)) * 2048 + hh * 128 + d2]
                = f2bf(o_acc[c2][j] * linv[j]);
        }
}

// ---------------- launcher ----------------

extern "C" void kernel_launch(void* const* d_in, const int* in_sizes, int n_in,
                              void* d_out, int out_size, void* d_ws, size_t ws_size,
                              hipStream_t stream) {
    const float* x    = (const float*)d_in[0];   // [2,2048,2048]
    const float* Wqkv = (const float*)d_in[1];   // [2048,6144]
    const float* bqkv = (const float*)d_in[2];   // [6144]
    const float* Wout = (const float*)d_in[3];   // [2048,2048]
    const float* bout = (const float*)d_in[4];   // [2048]
    float* out = (float*)d_out;                  // [2,2048,2048] fp32

    char* ws = (char*)d_ws;
    const size_t SZ = 16777216;                  // 16 MiB units
    u16* q   = (u16*)(ws);                       // [32][2048][128] bf16
    u16* kb  = (u16*)(ws + SZ);                  // same
    u16* v   = (u16*)(ws + 2 * SZ);              // same (dead after transpose)
    u16* vT  = (u16*)(ws + 3 * SZ);              // [32][128][2048] bf16
    u16* ao  = v;                                // attn output reuses v region
    u16* xb  = (u16*)(ws + 4 * SZ);              // x bf16 [4096][2048]
    u16* WqT = (u16*)(ws + 5 * SZ);              // Wqkv^T bf16 [6144][2048]
    u16* WoT = (u16*)(ws + 5 * SZ + 25165824);   // Wout^T bf16 [2048][2048]
    // total ws use: ~112 MiB

    k_cast<<<dim3(8192), dim3(256), 0, stream>>>(x, xb, 2097152);
    k_castT<<<dim3(192, 64), dim3(32, 8), 0, stream>>>(Wqkv, WqT, 2048, 6144);
    k_castT<<<dim3(64, 64), dim3(32, 8), 0, stream>>>(Wout, WoT, 2048, 2048);
    k_gemm_qkv<<<dim3(48, 32), dim3(256), 0, stream>>>(xb, WqT, bqkv, q, kb, v);
    k_transv<<<dim3(64, 4, 32), dim3(32, 8), 0, stream>>>(v, vT);
    k_attn<<<dim3(1024), dim3(256), 0, stream>>>(q, kb, vT, ao);
    k_gemm_out<<<dim3(16, 32), dim3(256), 0, stream>>>(ao, WoT, bout, out);
}

// Round 4
// 296.745 us; speedup vs baseline: 1.6211x; 1.1895x over previous
//
#include <hip/hip_runtime.h>

// Fused causal attention block: qkv = x@Wqkv+b; flash-attn(causal); out = attn@Wout+b
// B=2, S=2048, D=2048, H=16, Dh=128. All GEMM/attn compute in bf16 MFMA, fp32 accum.

typedef unsigned short u16;
typedef __attribute__((ext_vector_type(8))) short bf16x8;   // 8 bf16 (4 VGPRs)
typedef __attribute__((ext_vector_type(4))) float f32x4;

#define MFMA(a, b, c) __builtin_amdgcn_mfma_f32_16x16x32_bf16((a), (b), (c), 0, 0, 0)

__device__ __forceinline__ u16 f2bf(float f) {           // RNE fp32->bf16
    unsigned u = __builtin_bit_cast(unsigned, f);
    u += 0x7fffu + ((u >> 16) & 1u);
    return (u16)(u >> 16);
}

__device__ __forceinline__ void gload16(const void* g, void* l) {
    __builtin_amdgcn_global_load_lds(
        (const __attribute__((address_space(1))) void*)g,
        (__attribute__((address_space(3))) void*)l, 16, 0, 0);
}

// ---------------- cast / transpose helpers ----------------

__global__ __launch_bounds__(256) void k_cast(const float* __restrict__ src,
                                              u16* __restrict__ dst, int n4) {
    int i = blockIdx.x * 256 + threadIdx.x;
    if (i >= n4) return;
    float4 a = ((const float4*)src)[i];
    ushort4 r;
    r.x = f2bf(a.x); r.y = f2bf(a.y); r.z = f2bf(a.z); r.w = f2bf(a.w);
    ((ushort4*)dst)[i] = r;
}

// src [rows][cols] fp32 -> dst [cols][rows] bf16
__global__ __launch_bounds__(256) void k_castT(const float* __restrict__ src,
                                               u16* __restrict__ dst, int rows, int cols) {
    __shared__ float t[32][33];
    int c0 = blockIdx.x * 32, r0 = blockIdx.y * 32;
    int tx = threadIdx.x, ty = threadIdx.y;
#pragma unroll
    for (int i = 0; i < 4; ++i)
        t[ty + 8 * i][tx] = src[(size_t)(r0 + ty + 8 * i) * cols + (c0 + tx)];
    __syncthreads();
#pragma unroll
    for (int i = 0; i < 4; ++i)
        dst[(size_t)(c0 + ty + 8 * i) * rows + (r0 + tx)] = f2bf(t[tx][ty + 8 * i]);
}

// v [head][2048][128] bf16 -> vT [head][128][2048] bf16
__global__ __launch_bounds__(256) void k_transv(const u16* __restrict__ v,
                                                u16* __restrict__ vT) {
    __shared__ u16 t[32][33];
    int head = blockIdx.z;
    int s0 = blockIdx.x * 32, d0 = blockIdx.y * 32;
    const u16* vp = v + (size_t)head * 2048 * 128;
    u16* op = vT + (size_t)head * 128 * 2048;
    int tx = threadIdx.x, ty = threadIdx.y;
#pragma unroll
    for (int i = 0; i < 4; ++i)
        t[ty + 8 * i][tx] = vp[(size_t)(s0 + ty + 8 * i) * 128 + d0 + tx];
    __syncthreads();
#pragma unroll
    for (int i = 0; i < 4; ++i)
        op[(size_t)(d0 + ty + 8 * i) * 2048 + (s0 + tx)] = t[tx][ty + 8 * i];
}

// ---------------- GEMM core (m97 structure): C[128x128] tile, BK=32 ----------------
// A [M][K] bf16 row-major; BT [N][K] bf16 row-major (i.e. B transposed).

template <int K>
__device__ __forceinline__ void gemm_core(const u16* __restrict__ A,
                                          const u16* __restrict__ BT,
                                          int m0, int n0,
                                          f32x4 (&acc)[4][4],
                                          u16* As, u16* Bs) {
    const int tid = threadIdx.x, wave = tid >> 6, lane = tid & 63;
    const int wr = (wave >> 1) * 64, wc = (wave & 1) * 64;
    for (int k0 = 0; k0 < K; k0 += 32) {
        __syncthreads();   // previous compute done before LDS overwrite
#pragma unroll
        for (int i = 0; i < 2; ++i) {
            int cb = (i * 4 + wave) * 64;         // wave-uniform chunk base
            int c = cb + lane;
            int row = c >> 2, kk = (c & 3) * 8;   // 4 x 16B chunks per 32-elem row
            gload16(A + (size_t)(m0 + row) * K + k0 + kk, As + cb * 8);
            gload16(BT + (size_t)(n0 + row) * K + k0 + kk, Bs + cb * 8);
        }
        __syncthreads();   // vmcnt(0) drain before reads
        bf16x8 a[4], b[4];
#pragma unroll
        for (int m = 0; m < 4; ++m)
            a[m] = *(const bf16x8*)(As + (wr + m * 16 + (lane & 15)) * 32 + (lane >> 4) * 8);
#pragma unroll
        for (int n = 0; n < 4; ++n)
            b[n] = *(const bf16x8*)(Bs + (wc + n * 16 + (lane & 15)) * 32 + (lane >> 4) * 8);
        __builtin_amdgcn_s_setprio(1);
#pragma unroll
        for (int m = 0; m < 4; ++m)
#pragma unroll
            for (int n = 0; n < 4; ++n)
                acc[m][n] = MFMA(a[m], b[n], acc[m][n]);
        __builtin_amdgcn_s_setprio(0);
    }
}

// GEMM1: qkv = x@Wqkv + bqkv, scattered into q/k/v [B*H][S][Dh] bf16
__global__ __launch_bounds__(256) void k_gemm_qkv(const u16* __restrict__ A,
                                                  const u16* __restrict__ BT,
                                                  const float* __restrict__ bias,
                                                  u16* __restrict__ q,
                                                  u16* __restrict__ kbuf,
                                                  u16* __restrict__ v) {
    __shared__ __align__(16) u16 As[128 * 32];
    __shared__ __align__(16) u16 Bs[128 * 32];
    f32x4 acc[4][4] = {};
    // XCD-chunked remap (nwg = 48*32 = 1536, %8 == 0 -> simple bijection)
    const int orig = blockIdx.y * 48 + blockIdx.x;
    const int nb = (orig & 7) * 192 + (orig >> 3);
    const int m0 = (nb / 48) * 128, n0 = (nb % 48) * 128;
    gemm_core<2048>(A, BT, m0, n0, acc, As, Bs);

    const int tid = threadIdx.x, wave = tid >> 6, lane = tid & 63;
    const int wr = (wave >> 1) * 64, wc = (wave & 1) * 64;
    const int t = n0 >> 11;                      // 0=q 1=k 2=v (tile fits in one region)
    u16* dst = (t == 0) ? q : (t == 1) ? kbuf : v;
#pragma unroll
    for (int m = 0; m < 4; ++m)
#pragma unroll
        for (int n = 0; n < 4; ++n)
#pragma unroll
            for (int j = 0; j < 4; ++j) {
                int gr = m0 + wr + m * 16 + (lane >> 4) * 4 + j;   // b*S+s
                int gc = n0 + wc + n * 16 + (lane & 15);           // 3*H*Dh col
                float val = acc[m][n][j] + bias[gc];
                int bb = gr >> 11, s = gr & 2047;
                int rem = gc & 2047, h = rem >> 7, d = rem & 127;
                dst[((size_t)(bb * 16 + h) * 2048 + s) * 128 + d] = f2bf(val);
            }
}

// GEMM2: out = attn@Wout + bout (fp32 output)
__global__ __launch_bounds__(256) void k_gemm_out(const u16* __restrict__ A,
                                                  const u16* __restrict__ BT,
                                                  const float* __restrict__ bias,
                                                  float* __restrict__ out) {
    __shared__ __align__(16) u16 As[128 * 32];
    __shared__ __align__(16) u16 Bs[128 * 32];
    f32x4 acc[4][4] = {};
    // XCD-chunked remap (nwg = 16*32 = 512)
    const int orig = blockIdx.y * 16 + blockIdx.x;
    const int nb = (orig & 7) * 64 + (orig >> 3);
    const int m0 = (nb / 16) * 128, n0 = (nb % 16) * 128;
    gemm_core<2048>(A, BT, m0, n0, acc, As, Bs);

    const int tid = threadIdx.x, wave = tid >> 6, lane = tid & 63;
    const int wr = (wave >> 1) * 64, wc = (wave & 1) * 64;
#pragma unroll
    for (int m = 0; m < 4; ++m)
#pragma unroll
        for (int n = 0; n < 4; ++n)
#pragma unroll
            for (int j = 0; j < 4; ++j) {
                int gr = m0 + wr + m * 16 + (lane >> 4) * 4 + j;
                int gc = n0 + wc + n * 16 + (lane & 15);
                out[(size_t)gr * 2048 + gc] = acc[m][n][j] + bias[gc];
            }
}

// ---------------- flash attention (causal) v4 ----------------
// 512 blocks; causal PAIR scheduling (block = q-tiles {pair, 31-pair} = 33
// tile-units, perfectly balanced). 4 waves x 16 q-rows, KVB=64.
// K/V double-buffered in LDS via global_load_lds with PRE-SWIZZLED global
// source; raw s_barrier + counted vmcnt(8) so next tile's loads fly under
// compute (T3/T4). Softmax: defer-max (T13, THR=8 log2) + row-sum via MFMA
// against all-ones B (no shuffle-add reduction).
// q,k: [B*H][S][128] bf16. vT: [B*H][128][S] bf16. o: [B][S][H*128] bf16.
__global__ __launch_bounds__(256) void k_attn(const u16* __restrict__ q,
                                              const u16* __restrict__ k,
                                              const u16* __restrict__ vT,
                                              u16* __restrict__ o) {
    __shared__ __align__(16) u16 KsA[2 * 64 * 128];  // 32 KB dbuf, rows 256 B
    __shared__ __align__(16) u16 VsA[2 * 128 * 64];  // 32 KB dbuf, rows 128 B
    __shared__ __align__(16) u16 PsA[4 * 16 * 64];   // 8 KB, per-wave 16x64
    char* ksB = (char*)KsA;
    char* vsB = (char*)VsA;

    const int tid = threadIdx.x, wave = tid >> 6, lane = tid & 63;
    char* psB = (char*)PsA + wave * 2048;

    // XCD-chunked remap: 512 blocks -> each XCD a contiguous 64-chunk
    // (= 4 heads x 16 pairs; K/V L2-local).
    const int lin = blockIdx.x;
    const int dd = (lin & 7) * 64 + (lin >> 3);
    const int head = dd >> 4, pair = dd & 15;

    const u16* qh = q + (size_t)head * 2048 * 128;
    const u16* kh = k + (size_t)head * 2048 * 128;
    const u16* vh = vT + (size_t)head * 128 * 2048;
    const int bb = head >> 4, hh = head & 15;
    const float qscale = 0.1275293562566334f;        // (1/sqrt(128)) * log2(e)

    bf16x8 ones;
#pragma unroll
    for (int e = 0; e < 8; ++e) ones[e] = (short)0x3F80;   // bf16 1.0

    auto stage = [&](int kv0, int bufsel) {
        char* kd = ksB + bufsel * 16384;
        char* vd = vsB + bufsel * 16384;
#pragma unroll
        for (int i = 0; i < 4; ++i) {             // K tile 64x128
            int cb = (i * 4 + wave) * 64;         // wave-uniform chunk base
            int d = (cb + lane) * 16;
            int r = d >> 8;
            int co = (d & 255) ^ ((r & 7) << 4);  // pre-swizzled source col
            gload16(kh + (size_t)(kv0 + r) * 128 + (co >> 1), kd + cb * 16);
        }
#pragma unroll
        for (int i = 0; i < 4; ++i) {             // V^T tile 128x64
            int cb = (i * 4 + wave) * 64;
            int d = (cb + lane) * 16;
            int vr = d >> 7;
            int co = (d & 127) ^ ((vr & 7) << 4);
            gload16(vh + (size_t)vr * 2048 + kv0 + (co >> 1), vd + cb * 16);
        }
    };

#pragma unroll 1
    for (int qsel = 0; qsel < 2; ++qsel) {
        const int qi = qsel ? (31 - pair) : pair;
        const int q0 = qi * 64;
        const int ntile = qi + 1;

        bf16x8 qf[4];
        const int qr = q0 + wave * 16 + (lane & 15);
#pragma unroll
        for (int kt = 0; kt < 4; ++kt)
            qf[kt] = *(const bf16x8*)(qh + (size_t)qr * 128 + kt * 32 + (lane >> 4) * 8);

        f32x4 o_acc[8] = {};
        float m_r[4], l_r[4];
#pragma unroll
        for (int j = 0; j < 4; ++j) { m_r[j] = -1e30f; l_r[j] = 0.f; }

        stage(0, 0);                              // prologue: tile 0 in flight
        int buf = 0;

#pragma unroll 1
        for (int t = 0; t < ntile; ++t) {
            const int kv0 = t * 64;
            if (t + 1 < ntile) {
                stage(kv0 + 64, buf ^ 1);         // issue next tile early
                asm volatile("s_waitcnt vmcnt(8)" ::: "memory");  // cur tile done
            } else {
                asm volatile("s_waitcnt vmcnt(0)" ::: "memory");
            }
            __builtin_amdgcn_s_barrier();         // all waves: tile visible
            char* kb_ = ksB + buf * 16384;
            char* vb_ = vsB + buf * 16384;

            // S = Q K^T : D-layout row=(lane>>4)*4+j (q-local), col=c*16+(lane&15)
            f32x4 s_acc[4] = {};
            __builtin_amdgcn_s_setprio(1);
#pragma unroll
            for (int c = 0; c < 4; ++c) {
                int row = c * 16 + (lane & 15);
#pragma unroll
                for (int kt = 0; kt < 4; ++kt) {
                    bf16x8 kbf = *(const bf16x8*)(kb_ +
                        ((row * 256 + kt * 64 + (lane >> 4) * 16) ^ ((row & 7) << 4)));
                    s_acc[c] = MFMA(qf[kt], kbf, s_acc[c]);
                }
            }
            __builtin_amdgcn_s_setprio(0);

            const bool maskblk = (kv0 + 64 > q0);  // only the diagonal block
            float bm[4];
#pragma unroll
            for (int j = 0; j < 4; ++j) {
                int qg = q0 + wave * 16 + (lane >> 4) * 4 + j;
                float mx = -1e30f;
#pragma unroll
                for (int c = 0; c < 4; ++c) {
                    float sv = s_acc[c][j] * qscale;   // log2 domain
                    if (maskblk && (kv0 + c * 16 + (lane & 15)) > qg) sv = -1e30f;
                    s_acc[c][j] = sv;
                    mx = fmaxf(mx, sv);
                }
#pragma unroll
                for (int t2 = 1; t2 < 16; t2 <<= 1) mx = fmaxf(mx, __shfl_xor(mx, t2));
                bm[j] = mx;
            }
            // defer-max (T13): only rescale when the block max grew past THR=8
            bool grow = (bm[0] > m_r[0] + 8.f) | (bm[1] > m_r[1] + 8.f) |
                        (bm[2] > m_r[2] + 8.f) | (bm[3] > m_r[3] + 8.f);
            if (__any(grow)) {
#pragma unroll
                for (int j = 0; j < 4; ++j) {
                    float mnew = fmaxf(m_r[j], bm[j]);
                    float al = exp2f(m_r[j] - mnew);
                    m_r[j] = mnew;
                    l_r[j] *= al;
#pragma unroll
                    for (int c2 = 0; c2 < 8; ++c2) o_acc[c2][j] *= al;
                }
            }
#pragma unroll
            for (int j = 0; j < 4; ++j)
#pragma unroll
                for (int c = 0; c < 4; ++c)
                    s_acc[c][j] = exp2f(s_acc[c][j] - m_r[j]);   // p <= 2^8

            // bounce P (D-layout) -> per-wave LDS -> A-layout fragments (no barrier)
#pragma unroll
            for (int c = 0; c < 4; ++c)
#pragma unroll
                for (int j = 0; j < 4; ++j) {
                    int row = (lane >> 4) * 4 + j;
                    *(u16*)(psB + ((row * 128 + (c * 16 + (lane & 15)) * 2) ^ ((row & 7) << 4)))
                        = f2bf(s_acc[c][j]);
                }
            bf16x8 pf[2];
#pragma unroll
            for (int kt = 0; kt < 2; ++kt) {
                int row2 = lane & 15;
                pf[kt] = *(const bf16x8*)(psB +
                    ((row2 * 128 + kt * 64 + (lane >> 4) * 16) ^ ((row2 & 7) << 4)));
            }

            __builtin_amdgcn_s_setprio(1);
            // row-sum of bf16 P via MFMA vs all-ones B (exact match with PV numerics)
            f32x4 rs_acc = {};
            rs_acc = MFMA(pf[0], ones, rs_acc);
            rs_acc = MFMA(pf[1], ones, rs_acc);
#pragma unroll
            for (int c2 = 0; c2 < 8; ++c2) {
#pragma unroll
                for (int kt = 0; kt < 2; ++kt) {
                    int row = c2 * 16 + (lane & 15);
                    bf16x8 vf = *(const bf16x8*)(vb_ +
                        ((row * 128 + kt * 64 + (lane >> 4) * 16) ^ ((row & 7) << 4)));
                    o_acc[c2] = MFMA(pf[kt], vf, o_acc[c2]);
                }
            }
            __builtin_amdgcn_s_setprio(0);
#pragma unroll
            for (int j = 0; j < 4; ++j) l_r[j] += rs_acc[j];

            __builtin_amdgcn_s_barrier();         // reads done before overwrite
            buf ^= 1;
        }

        float linv[4];
#pragma unroll
        for (int j = 0; j < 4; ++j) linv[j] = 1.0f / l_r[j];
#pragma unroll
        for (int c2 = 0; c2 < 8; ++c2)
#pragma unroll
            for (int j = 0; j < 4; ++j) {
                int qg = q0 + wave * 16 + (lane >> 4) * 4 + j;
                int d2 = c2 * 16 + (lane & 15);
                o[((size_t)(bb * 2048 + qg)) * 2048 + hh * 128 + d2]
                    = f2bf(o_acc[c2][j] * linv[j]);
            }
    }
}

// ---------------- launcher ----------------

extern "C" void kernel_launch(void* const* d_in, const int* in_sizes, int n_in,
                              void* d_out, int out_size, void* d_ws, size_t ws_size,
                              hipStream_t stream) {
    const float* x    = (const float*)d_in[0];   // [2,2048,2048]
    const float* Wqkv = (const float*)d_in[1];   // [2048,6144]
    const float* bqkv = (const float*)d_in[2];   // [6144]
    const float* Wout = (const float*)d_in[3];   // [2048,2048]
    const float* bout = (const float*)d_in[4];   // [2048]
    float* out = (float*)d_out;                  // [2,2048,2048] fp32

    char* ws = (char*)d_ws;
    const size_t SZ = 16777216;                  // 16 MiB units
    u16* q   = (u16*)(ws);                       // [32][2048][128] bf16
    u16* kb  = (u16*)(ws + SZ);                  // same
    u16* v   = (u16*)(ws + 2 * SZ);              // same (dead after transpose)
    u16* vT  = (u16*)(ws + 3 * SZ);              // [32][128][2048] bf16
    u16* ao  = v;                                // attn output reuses v region
    u16* xb  = (u16*)(ws + 4 * SZ);              // x bf16 [4096][2048]
    u16* WqT = (u16*)(ws + 5 * SZ);              // Wqkv^T bf16 [6144][2048]
    u16* WoT = (u16*)(ws + 5 * SZ + 25165824);   // Wout^T bf16 [2048][2048]
    // total ws use: ~112 MiB

    k_cast<<<dim3(8192), dim3(256), 0, stream>>>(x, xb, 2097152);
    k_castT<<<dim3(192, 64), dim3(32, 8), 0, stream>>>(Wqkv, WqT, 2048, 6144);
    k_castT<<<dim3(64, 64), dim3(32, 8), 0, stream>>>(Wout, WoT, 2048, 2048);
    k_gemm_qkv<<<dim3(48, 32), dim3(256), 0, stream>>>(xb, WqT, bqkv, q, kb, v);
    k_transv<<<dim3(64, 4, 32), dim3(32, 8), 0, stream>>>(v, vT);
    k_attn<<<dim3(512), dim3(256), 0, stream>>>(q, kb, vT, ao);
    k_gemm_out<<<dim3(16, 32), dim3(256), 0, stream>>>(ao, WoT, bout, out);
}